// Round 4
// baseline (500.232 us; speedup 1.0000x reference)
//
#include <hip/hip_runtime.h>

// PLIF forward scan: v = beta*v + x_t; s = (v-1 >= 0); v *= (1-s)
// T=32 sequential in registers; B*N lanes fully parallel.
//
// R1: simple loop, VGPR=28, ~170us, 2.8 TB/s — 1 load in flight/wave.
// R3: PF=4 ring + __builtin_nontemporal stores: 205us but PASSED => builtin
//     nt stores are correctness-safe; interleaved nt was a perf loss.
// R4: chunk-8 double buffer in plain C++: scheduler sank the loads (VGPR=36).
// R5: inline-asm load dwordx4, 2x8 buffers, vmcnt(8), C++ stores: 170us,
//     2.35 TB/s, PASSED. fillBuffer hits 80% HBM peak at 9.8% occupancy =>
//     occupancy is NOT the bandwidth lever on this chip.
// R6/R7: moved stores into inline asm ("v"(s) source) -> FAILED, absmax ~10
//     garbage. ROOT CAUSE (explains both): VMEM stores read their data VGPRs
//     asynchronously; sources must stay stable until the store's vmcnt
//     retires. The compiler sees the asm store as the last use of s and
//     reuses those VGPRs immediately for the next iteration => in-flight
//     stores snapshot garbage. Plain/builtin stores are hazard-tracked by
//     the backend; asm stores are not. NEVER hand-roll stores whose source
//     regs get recycled.
// R8: R7's structure, compiler-managed stores. (Round 3 bench was an infra
//     failure — container died twice, kernel never ran — resubmitting
//     unchanged so the next data point cleanly tests the store-hazard fix.)
//     - Scan phase: bit-pack spikes (32t x 4ch -> four u32 VGPRs). Phase is
//       loads-only => the hand vmcnt ladder is exact by construction.
//     - Epilogue: expand bits -> float4, __builtin_nontemporal_store burst
//       (write-once data; don't evict the exactly-L3-sized input from L3).
//       All stores data-depend on final sp and every WAITN has a "memory"
//       clobber, so compiler stores cannot migrate into the ladder.
//     - launch_bounds(256,4): 128-VGPR cap, demand ~60-90 => zero spill risk.

#define T_STEPS 32
#define CH 4

typedef float vfloat4 __attribute__((ext_vector_type(4)));

// Issue CH independent 16B loads into buf (volatile: pinned in program order).
// stride16 is wave-uniform so per-t offsets fold cheaply; voff is one v_add.
#define ISSUE(buf, tc)                                                        \
    _Pragma("unroll")                                                         \
    for (int k = 0; k < CH; ++k) {                                            \
        unsigned voff = base16 + (unsigned)((tc) + k) * stride16;             \
        asm volatile("global_load_dwordx4 %0, %1, %2"                         \
                     : "=v"(buf[k])                                           \
                     : "v"(voff), "s"(xp));                                   \
    }

// Wait until only the N newest VMEM ops remain outstanding. The VMEM stream
// contains ONLY our loads during the scan, so counts are exact. The "memory"
// clobber doubles as a compiler fence: no compiler-generated memory op may
// cross into the counted region.
#define WAITN(n) asm volatile("s_waitcnt vmcnt(" #n ")" ::: "memory")

// Data-dependency fence: consumers of buf must read the post-wait value,
// so the VALU consume cannot be hoisted above the s_waitcnt (rule #18).
#define FENCE(buf)                                                            \
    _Pragma("unroll")                                                         \
    for (int k = 0; k < CH; ++k) asm volatile("" : "+v"(buf[k]));

// Scan one chunk: update v, record spike bits. NO stores in the scan phase.
// All indices are compile-time constants after unrolling => sp[] stays in
// VGPRs (rule #20 satisfied).
#define SCAN(buf, tc)                                                         \
    _Pragma("unroll")                                                         \
    for (int k = 0; k < CH; ++k) {                                            \
        vfloat4 xt = buf[k];                                                  \
        _Pragma("unroll")                                                     \
        for (int c = 0; c < 4; ++c) {                                         \
            /* separate mul/add rounding: matches XLA non-contracted HLO */   \
            v[c] = __fadd_rn(__fmul_rn(beta, v[c]), xt[c]);                   \
            /* s = Heaviside(v - 1), reference op order */                    \
            float d  = __fadd_rn(v[c], -1.0f);                                \
            float sf = (d >= 0.0f) ? 1.0f : 0.0f;                             \
            sp[c] |= ((d >= 0.0f) ? 1u : 0u) << ((tc) + k);                   \
            /* hard reset, exact since sf in {0,1} */                         \
            v[c] *= (1.0f - sf);                                              \
        }                                                                     \
    }

__global__ __launch_bounds__(256, 4) void plif_fwd_kernel(
    const vfloat4* __restrict__ xp, const float* __restrict__ beta_raw,
    vfloat4* __restrict__ op, int bn4)
{
    int i = blockIdx.x * blockDim.x + threadIdx.x;
    if (i >= bn4) return;

    // beta = sigmoid(beta_raw); precise expf matches reference trajectory.
    float beta = 1.0f / (1.0f + expf(-beta_raw[0]));
    // Pin beta (and its uniform load + compiler wait) BEFORE the first ISSUE,
    // so no compiler-inserted VMEM op lands inside our counted pipeline.
    asm volatile("" : "+v"(beta));

    unsigned base16   = (unsigned)i * 16u;        // byte offset of lane, <4GB
    unsigned stride16 = (unsigned)bn4 * 16u;      // byte stride per t-step

    vfloat4 v = (vfloat4)(0.0f, 0.0f, 0.0f, 0.0f);
    unsigned sp[4] = {0u, 0u, 0u, 0u};            // bit t of sp[c] = spike
    vfloat4 A[CH], B[CH];

    // Loads-only ladder: steady state keeps 8 x 16B loads in flight per lane.
    ISSUE(A, 0);                                  // outstanding: A(4)
    ISSUE(B, 4);                                  // outstanding: A(4) B(4)
    WAITN(4); FENCE(A); SCAN(A,  0); ISSUE(A,  8);
    WAITN(4); FENCE(B); SCAN(B,  4); ISSUE(B, 12);
    WAITN(4); FENCE(A); SCAN(A,  8); ISSUE(A, 16);
    WAITN(4); FENCE(B); SCAN(B, 12); ISSUE(B, 20);
    WAITN(4); FENCE(A); SCAN(A, 16); ISSUE(A, 24);
    WAITN(4); FENCE(B); SCAN(B, 20); ISSUE(B, 28);
    WAITN(4); FENCE(A); SCAN(A, 24);
    WAITN(0); FENCE(B); SCAN(B, 28);

    // Pure write burst: expand bits -> float4. Compiler-managed nt stores:
    // the backend tracks the store-source VGPR hazard (the R6/R7 bug) and
    // keeps as many stores in flight as registers allow.
    _Pragma("unroll")
    for (int t = 0; t < T_STEPS; ++t) {
        vfloat4 s;
        _Pragma("unroll")
        for (int c = 0; c < 4; ++c)
            s[c] = ((sp[c] >> t) & 1u) ? 1.0f : 0.0f;
        __builtin_nontemporal_store(s, &op[(unsigned)i + (unsigned)t * (unsigned)bn4]);
    }
}

extern "C" void kernel_launch(void* const* d_in, const int* in_sizes, int n_in,
                              void* d_out, int out_size, void* d_ws, size_t ws_size,
                              hipStream_t stream) {
    const float* x        = (const float*)d_in[0];
    const float* beta_raw = (const float*)d_in[1];
    float* out            = (float*)d_out;

    int total = in_sizes[0];        // T*B*N = 67,108,864
    int bn    = total / T_STEPS;    // B*N   =  2,097,152
    int bn4   = bn / 4;             // float4 lanes = 524,288

    dim3 block(256);
    dim3 grid((bn4 + block.x - 1) / block.x);
    plif_fwd_kernel<<<grid, block, 0, stream>>>(
        (const vfloat4*)x, beta_raw, (vfloat4*)out, bn4);
}

// Round 5
// 468.769 us; speedup vs baseline: 1.0671x; 1.0671x over previous
//
#include <hip/hip_runtime.h>

// PLIF forward scan: v = beta*v + x_t; s = (v-1 >= 0); v *= (1-s)
// T=32 sequential in registers; B*N lanes fully parallel.
//
// R1: simple loop, VGPR=28, ~170us, 2.8 TB/s.
// R3: PF=4 ring + nt stores: 205us. R4: C++ dbuf: loads sank. R5: asm-load
//     pipeline, C++ stores: 170us PASSED. fillBuffer: 6.4 TB/s @ 9.8% occ.
// R6/R7: inline-asm STORES -> garbage. Store source VGPRs are read async;
//     compiler recycles them after the asm. Loads-in-asm ok, stores never.
// R8: bit-packed scan + nt store burst: PASSED 193us. nt stores RAISED both
//     FETCH (131->156MB) and WRITE (262->311MB) ~19% and cost 13% time.
//     Two independent measurements (R3, R8): nt stores are a loss. Dropped.
//     Structure-invariance (R1/R5/R8 all ~170us) + copy ubench at 6.3 TB/s
//     => limiter is chip-level READ/WRITE STREAM MIXING + L3 write-thrash
//     (input is exactly L3-sized; half re-fetched every iteration), not
//     wave schedule.
// R9 (this): two single-direction kernels.
//     k1 (pure read):  scan 256MiB input -> 8MiB bit-packed spikes
//                      (32t x 4ch per thread = uint4), stored into the
//                      output buffer's own plane-0 slot out[i].
//     k2 (pure write): thread i reads its uint4 bits from out[i] (L3-hot),
//                      expands to 32 float4 planes, overwriting plane 0
//                      last-after-load (in-thread RAW only; thread i is the
//                      sole reader AND sole writer of out[i] => race-free;
//                      k1->k2 visibility via same-stream kernel ordering).
//     Each kernel is now copy/fill-shaped, which this chip runs at 6.3-6.4
//     TB/s vs our mixed 3.1.

#define T_STEPS 32
#define CH 4

typedef float    vfloat4 __attribute__((ext_vector_type(4)));
typedef unsigned vuint4  __attribute__((ext_vector_type(4)));

// Issue CH independent 16B loads into buf (volatile: pinned in program order).
#define ISSUE(buf, tc)                                                        \
    _Pragma("unroll")                                                         \
    for (int k = 0; k < CH; ++k) {                                            \
        unsigned voff = base16 + (unsigned)((tc) + k) * stride16;             \
        asm volatile("global_load_dwordx4 %0, %1, %2"                         \
                     : "=v"(buf[k])                                           \
                     : "v"(voff), "s"(xp));                                   \
    }

// Wait until only the N newest VMEM ops remain outstanding. Scan phase is
// loads-only, so counts are exact by construction. "memory" clobber keeps
// compiler-generated memory ops out of the counted region.
#define WAITN(n) asm volatile("s_waitcnt vmcnt(" #n ")" ::: "memory")

// Data-dependency fence: consumers must read the post-wait value (rule #18).
#define FENCE(buf)                                                            \
    _Pragma("unroll")                                                         \
    for (int k = 0; k < CH; ++k) asm volatile("" : "+v"(buf[k]));

// Scan one chunk: update v, record spike bits. NO stores in the scan phase.
// All indices compile-time after unrolling => sp[] stays in VGPRs (rule #20).
#define SCAN(buf, tc)                                                         \
    _Pragma("unroll")                                                         \
    for (int k = 0; k < CH; ++k) {                                            \
        vfloat4 xt = buf[k];                                                  \
        _Pragma("unroll")                                                     \
        for (int c = 0; c < 4; ++c) {                                         \
            /* separate mul/add rounding: matches XLA non-contracted HLO */   \
            v[c] = __fadd_rn(__fmul_rn(beta, v[c]), xt[c]);                   \
            /* s = Heaviside(v - 1), reference op order */                    \
            float d  = __fadd_rn(v[c], -1.0f);                                \
            float sf = (d >= 0.0f) ? 1.0f : 0.0f;                             \
            sp[c] |= ((d >= 0.0f) ? 1u : 0u) << ((tc) + k);                   \
            /* hard reset, exact since sf in {0,1} */                         \
            v[c] *= (1.0f - sf);                                              \
        }                                                                     \
    }

// ---- k1: pure-read scan, 8 MiB bit output -------------------------------
__global__ __launch_bounds__(256, 4) void plif_scan_kernel(
    const vfloat4* __restrict__ xp, const float* __restrict__ beta_raw,
    vuint4* __restrict__ bp, int bn4)
{
    int i = blockIdx.x * blockDim.x + threadIdx.x;
    if (i >= bn4) return;

    // beta = sigmoid(beta_raw); precise expf matches reference trajectory.
    float beta = 1.0f / (1.0f + expf(-beta_raw[0]));
    // Pin beta (and its uniform load + compiler wait) BEFORE the first ISSUE.
    asm volatile("" : "+v"(beta));

    unsigned base16   = (unsigned)i * 16u;        // byte offset of lane, <4GB
    unsigned stride16 = (unsigned)bn4 * 16u;      // byte stride per t-step

    vfloat4 v = (vfloat4)(0.0f, 0.0f, 0.0f, 0.0f);
    unsigned sp[4] = {0u, 0u, 0u, 0u};            // bit t of sp[c] = spike
    vfloat4 A[CH], B[CH];

    // Loads-only ladder: steady state keeps 8 x 16B loads in flight per lane.
    ISSUE(A, 0);
    ISSUE(B, 4);
    WAITN(4); FENCE(A); SCAN(A,  0); ISSUE(A,  8);
    WAITN(4); FENCE(B); SCAN(B,  4); ISSUE(B, 12);
    WAITN(4); FENCE(A); SCAN(A,  8); ISSUE(A, 16);
    WAITN(4); FENCE(B); SCAN(B, 12); ISSUE(B, 20);
    WAITN(4); FENCE(A); SCAN(A, 16); ISSUE(A, 24);
    WAITN(4); FENCE(B); SCAN(B, 20); ISSUE(B, 28);
    WAITN(4); FENCE(A); SCAN(A, 24);
    WAITN(0); FENCE(B); SCAN(B, 28);

    // 16B bit-packed result -> plane-0 slot i of the output buffer.
    // Plain store (nt proven harmful); compiler handles the source hazard.
    vuint4 bits; bits[0]=sp[0]; bits[1]=sp[1]; bits[2]=sp[2]; bits[3]=sp[3];
    bp[i] = bits;
}

// ---- k2: pure-write expansion ------------------------------------------
__global__ __launch_bounds__(256, 4) void plif_expand_kernel(
    vfloat4* op, int bn4)
{
    int i = blockIdx.x * blockDim.x + threadIdx.x;
    if (i >= bn4) return;

    // Thread i is the SOLE reader and sole writer of out[i]: load bits, then
    // overwrite. The asm ties the loaded value and clobbers memory, so the
    // compiler cannot reorder the plane-0 store above the load (TBAA-proof).
    vuint4 u = *((const vuint4*)op + i);
    asm volatile("" : "+v"(u) :: "memory");

    _Pragma("unroll")
    for (int t = 0; t < T_STEPS; ++t) {
        vfloat4 s;
        _Pragma("unroll")
        for (int c = 0; c < 4; ++c)
            s[c] = ((u[c] >> t) & 1u) ? 1.0f : 0.0f;
        op[i + t * bn4] = s;   // plain coalesced store burst
    }
}

extern "C" void kernel_launch(void* const* d_in, const int* in_sizes, int n_in,
                              void* d_out, int out_size, void* d_ws, size_t ws_size,
                              hipStream_t stream) {
    const float* x        = (const float*)d_in[0];
    const float* beta_raw = (const float*)d_in[1];
    float* out            = (float*)d_out;

    int total = in_sizes[0];        // T*B*N = 67,108,864
    int bn    = total / T_STEPS;    // B*N   =  2,097,152
    int bn4   = bn / 4;             // float4 lanes = 524,288

    dim3 block(256);
    dim3 grid((bn4 + block.x - 1) / block.x);
    // Same stream: k2 sees k1's bits (kernel-completion release fence);
    // no sync calls => graph-capture safe.
    plif_scan_kernel<<<grid, block, 0, stream>>>(
        (const vfloat4*)x, beta_raw, (vuint4*)out, bn4);
    plif_expand_kernel<<<grid, block, 0, stream>>>(
        (vfloat4*)out, bn4);
}